// Round 2
// baseline (1456.252 us; speedup 1.0000x reference)
//
#include <hip/hip_runtime.h>
#include <stdint.h>

#define TOKENS 4096
#define DIM    1024
#define HDIM   4096
#define NEXP   8
#define NPAD   5120
#define ALPHA  0.001f
#define BETA   0.001f
#define GAMMA  0.001f

// ---- workspace layout (bytes) ----
#define WS_CNT      0          // int[8]
#define WS_SUMP     32         // float[8]
#define WS_PSUM     64         // float[8]
#define WS_PSUMSQ   96         // float[8]
#define WS_OFFP     128        // int[16] (use 9)
#define WS_AVGP     192        // float[8]
#define WS_LOSSP    224        // float[1]
#define WS_OFFSQ    256        // float[8]
#define WS_YNORM    512                    // float[5120] -> ends 20992
#define WS_ZERO_END 20992
#define WS_LIST     21504                  // int[8*4096]
#define WS_XB       152576                 // bf16[4096*1024]
#define WS_W1T      8541184                // bf16[8*4096*1024]  (later aliased by ybuf)
#define WS_W2T      75650048               // bf16[8*1024*4096]
#define WS_HBUF     142758912              // bf16[5120*4096]
#define WS_YT       184701952              // bf16[1024*5120]
#define WS_TOTAL    195187712
#define WS_YBUF     WS_W1T                 // f32[2][5120*1024] = 41.9MB <= 67MB region
#define YBS         (NPAD * DIM)           // elements per slice

typedef __bf16 bf16x8 __attribute__((ext_vector_type(8)));
typedef float  f32x4  __attribute__((ext_vector_type(4)));
typedef unsigned short u16x4 __attribute__((ext_vector_type(4)));

__device__ __forceinline__ unsigned short f2bf(float f) {
    union { float f; unsigned u; } v; v.f = f;
    unsigned r = v.u + 0x7fffu + ((v.u >> 16) & 1u);   // RNE
    return (unsigned short)(r >> 16);
}

// ---------------- K0a: x f32 -> bf16 ----------------
__global__ void k_cvt_x(const float* __restrict__ x, unsigned short* __restrict__ xb) {
    const int n4 = TOKENS * DIM / 4;
    for (int i = blockIdx.x * blockDim.x + threadIdx.x; i < n4; i += gridDim.x * blockDim.x) {
        float4 v = ((const float4*)x)[i];
        u16x4 o;
        o[0] = f2bf(v.x); o[1] = f2bf(v.y); o[2] = f2bf(v.z); o[3] = f2bf(v.w);
        ((u16x4*)xb)[i] = o;
    }
}

// ---------------- K0b: transpose + cvt  (out[c][r] = in[r][c]), 64x64 tiles ----------------
__global__ __launch_bounds__(256) void k_transpose_cvt(
        const float* __restrict__ in, unsigned short* __restrict__ out, int R, int C) {
    __shared__ float tile[64][65];
    const float* inp = in + (size_t)blockIdx.z * R * C;
    unsigned short* outp = out + (size_t)blockIdx.z * R * C;
    int r0 = blockIdx.y * 64, c0 = blockIdx.x * 64;
    int tx = threadIdx.x & 63, ty = threadIdx.x >> 6;  // ty 0..3
#pragma unroll
    for (int j = 0; j < 16; j++)
        tile[ty + 4 * j][tx] = inp[(size_t)(r0 + ty + 4 * j) * C + c0 + tx];
    __syncthreads();
#pragma unroll
    for (int j = 0; j < 16; j++)
        outp[(size_t)(c0 + ty + 4 * j) * R + r0 + tx] = f2bf(tile[tx][ty + 4 * j]);
}

// ---------------- K1: gating ----------------
__global__ __launch_bounds__(1024) void k_gate(
        const float* __restrict__ x, const float* __restrict__ gw, const float* __restrict__ gb,
        int* __restrict__ cnt, float* __restrict__ sump,
        float* __restrict__ psum, float* __restrict__ psumsq, int* __restrict__ list) {
    __shared__ float gwT[NEXP * DIM];
    __shared__ float bacc[3 * NEXP];
    int tid = threadIdx.x;
    if (tid < 3 * NEXP) bacc[tid] = 0.f;
    for (int i = tid; i < DIM * NEXP; i += 1024) {
        int d = i >> 3, e = i & 7;
        gwT[e * DIM + d] = gw[i];
    }
    __syncthreads();
    int wv = tid >> 6, l = tid & 63;
    int t = blockIdx.x * 16 + wv;
    float acc[8];
#pragma unroll
    for (int e = 0; e < 8; e++) acc[e] = 0.f;
    const float* xr = x + (size_t)t * DIM;
#pragma unroll
    for (int j = 0; j < 16; j++) {
        float xv = xr[l + 64 * j];
#pragma unroll
        for (int e = 0; e < 8; e++) acc[e] += xv * gwT[e * DIM + l + 64 * j];
    }
#pragma unroll
    for (int e = 0; e < 8; e++) {
#pragma unroll
        for (int s = 32; s > 0; s >>= 1) acc[e] += __shfl_xor(acc[e], s);
    }
    if (l == 0) {
        float lg[8], mx = -1e30f;
#pragma unroll
        for (int e = 0; e < 8; e++) { lg[e] = acc[e] + gb[e]; mx = fmaxf(mx, lg[e]); }
        float p[8], se = 0.f;
#pragma unroll
        for (int e = 0; e < 8; e++) { p[e] = __expf(lg[e] - mx); se += p[e]; }
        float inv = 1.f / se;
        int arg = 0; float best = lg[0];
#pragma unroll
        for (int e = 1; e < 8; e++) if (lg[e] > best) { best = lg[e]; arg = e; }
        float ptop = p[arg] * inv;
        int pos = atomicAdd(&cnt[arg], 1);
        list[arg * TOKENS + pos] = t;
        atomicAdd(&bacc[arg], ptop);
#pragma unroll
        for (int e = 0; e < 8; e++) {
            float pe = p[e] * inv;
            atomicAdd(&bacc[8 + e], pe);
            atomicAdd(&bacc[16 + e], pe * pe);
        }
    }
    __syncthreads();
    if (tid < 8) {
        atomicAdd(&sump[tid], bacc[tid]);
        atomicAdd(&psum[tid], bacc[8 + tid]);
        atomicAdd(&psumsq[tid], bacc[16 + tid]);
    }
}

// ---------------- K2: finalize gating ----------------
__global__ void k_finalize_gate(const int* __restrict__ cnt, const float* __restrict__ sump,
                                const float* __restrict__ psum, const float* __restrict__ psumsq,
                                int* __restrict__ offp, float* __restrict__ avgp,
                                float* __restrict__ lossp) {
    if (threadIdx.x == 0) {
        int off = 0; float aux = 0.f, var = 0.f;
        for (int e = 0; e < 8; e++) {
            offp[e] = off;
            int c = cnt[e];
            off += ((c + 127) / 128) * 128;
            float cf = (float)c;
            avgp[e] = (c > 0) ? sump[e] / cf : 0.f;
            float u = cf / (float)TOKENS;
            aux += u * u;
            var += psumsq[e] - psum[e] * psum[e] / (float)TOKENS;
        }
        offp[8] = off;
        aux *= (float)NEXP;
        float varloss = -var / ((float)TOKENS * (float)NEXP);
        lossp[0] = ALPHA * aux + GAMMA * varloss;
    }
}

// ---------------- K3: GEMM1  H = relu(X_e @ w1[e] + b1[e]) ----------------
__global__ __launch_bounds__(256) void k_gemm1(
        const unsigned short* __restrict__ xb, const unsigned short* __restrict__ w1t,
        const float* __restrict__ b1, const int* __restrict__ cnt, const int* __restrict__ offp,
        const int* __restrict__ list, unsigned short* __restrict__ Hbuf) {
    __shared__ unsigned short ldsA[128 * 32];
    __shared__ unsigned short ldsB[128 * 32];
    int ct = blockIdx.x, rt = blockIdx.y;
    int prow0 = rt * 128;
    if (prow0 >= offp[8]) return;
    int e = 0;
#pragma unroll
    for (int k = 1; k < 8; k++) if (prow0 >= offp[k]) e = k;
    int offe = offp[e], row0 = prow0 - offe, cnt_e = cnt[e];
    int tid = threadIdx.x, wv = tid >> 6, l = tid & 63;
    int wr = wv >> 1, wc = wv & 1;
    int t0 = list[e * TOKENS + min(row0 + l, cnt_e - 1)];
    int t1 = list[e * TOKENS + min(row0 + 64 + l, cnt_e - 1)];
    const unsigned short* srcA0 = xb + (size_t)t0 * DIM + wv * 8;
    const unsigned short* srcA1 = xb + (size_t)t1 * DIM + wv * 8;
    const unsigned short* srcB0 = w1t + ((size_t)e * HDIM + ct * 128 + l) * DIM + wv * 8;
    const unsigned short* srcB1 = w1t + ((size_t)e * HDIM + ct * 128 + 64 + l) * DIM + wv * 8;
    f32x4 acc[4][4] = {};
    bf16x8 sa0[2], sa1[2], sb0[2], sb1[2];
    const int NK = DIM / 32;
#pragma unroll
    for (int p = 0; p < 2; p++) {
        int kk = p * 32;
        sa0[p] = *(const bf16x8*)(srcA0 + kk);
        sa1[p] = *(const bf16x8*)(srcA1 + kk);
        sb0[p] = *(const bf16x8*)(srcB0 + kk);
        sb1[p] = *(const bf16x8*)(srcB1 + kk);
    }
    for (int i = 0; i < NK; i++) {
        int cur = i & 1;
        __syncthreads();
        *(bf16x8*)(ldsA + (wv * 128 + l) * 8)      = sa0[cur];
        *(bf16x8*)(ldsA + (wv * 128 + 64 + l) * 8) = sa1[cur];
        *(bf16x8*)(ldsB + (wv * 128 + l) * 8)      = sb0[cur];
        *(bf16x8*)(ldsB + (wv * 128 + 64 + l) * 8) = sb1[cur];
        __syncthreads();
        if (i + 2 < NK) {
            int kk = (i + 2) * 32;
            sa0[cur] = *(const bf16x8*)(srcA0 + kk);
            sa1[cur] = *(const bf16x8*)(srcA1 + kk);
            sb0[cur] = *(const bf16x8*)(srcB0 + kk);
            sb1[cur] = *(const bf16x8*)(srcB1 + kk);
        }
        int g = l >> 4, rr = l & 15;
        bf16x8 a[4], b[4];
#pragma unroll
        for (int m = 0; m < 4; m++) a[m] = *(const bf16x8*)(ldsA + (g * 128 + wr * 64 + m * 16 + rr) * 8);
#pragma unroll
        for (int n = 0; n < 4; n++) b[n] = *(const bf16x8*)(ldsB + (g * 128 + wc * 64 + n * 16 + rr) * 8);
#pragma unroll
        for (int m = 0; m < 4; m++)
#pragma unroll
            for (int n = 0; n < 4; n++)
                acc[m][n] = __builtin_amdgcn_mfma_f32_16x16x32_bf16(a[m], b[n], acc[m][n], 0, 0, 0);
    }
    int g = l >> 4, rr = l & 15;
#pragma unroll
    for (int n = 0; n < 4; n++) {
        int colg = ct * 128 + wc * 64 + n * 16 + rr;
        float bv = b1[e * HDIM + colg];
#pragma unroll
        for (int m = 0; m < 4; m++) {
#pragma unroll
            for (int j = 0; j < 4; j++) {
                int rloc = row0 + wr * 64 + m * 16 + g * 4 + j;
                if (rloc < cnt_e) {
                    float v = fmaxf(acc[m][n][j] + bv, 0.f);
                    Hbuf[(size_t)(offe + rloc) * HDIM + colg] = f2bf(v);
                }
            }
        }
    }
}

// ---------------- K4: GEMM2 split-K  ybuf[s] = H_e @ w2[e] (K half s) ----------------
__global__ __launch_bounds__(256) void k_gemm2(
        const unsigned short* __restrict__ Hbuf, const unsigned short* __restrict__ w2t,
        const int* __restrict__ cnt, const int* __restrict__ offp,
        float* __restrict__ ybuf) {
    __shared__ unsigned short ldsA[128 * 32];
    __shared__ unsigned short ldsB[128 * 32];
    int ct = blockIdx.x, rt = blockIdx.y, s = blockIdx.z;
    int prow0 = rt * 128;
    if (prow0 >= offp[8]) return;
    int e = 0;
#pragma unroll
    for (int k = 1; k < 8; k++) if (prow0 >= offp[k]) e = k;
    int offe = offp[e];
    int tid = threadIdx.x, wv = tid >> 6, l = tid & 63;
    int wr = wv >> 1, wc = wv & 1;
    const size_t kbase = (size_t)s * (HDIM / 2) + wv * 8;
    const unsigned short* srcA0 = Hbuf + (size_t)(prow0 + l) * HDIM + kbase;
    const unsigned short* srcA1 = Hbuf + (size_t)(prow0 + 64 + l) * HDIM + kbase;
    const unsigned short* srcB0 = w2t + ((size_t)e * DIM + ct * 128 + l) * HDIM + kbase;
    const unsigned short* srcB1 = w2t + ((size_t)e * DIM + ct * 128 + 64 + l) * HDIM + kbase;
    f32x4 acc[4][4] = {};
    bf16x8 sa0[2], sa1[2], sb0[2], sb1[2];
    const int NK = HDIM / 2 / 32;   // 64
#pragma unroll
    for (int p = 0; p < 2; p++) {
        int kk = p * 32;
        sa0[p] = *(const bf16x8*)(srcA0 + kk);
        sa1[p] = *(const bf16x8*)(srcA1 + kk);
        sb0[p] = *(const bf16x8*)(srcB0 + kk);
        sb1[p] = *(const bf16x8*)(srcB1 + kk);
    }
    for (int i = 0; i < NK; i++) {
        int cur = i & 1;
        __syncthreads();
        *(bf16x8*)(ldsA + (wv * 128 + l) * 8)      = sa0[cur];
        *(bf16x8*)(ldsA + (wv * 128 + 64 + l) * 8) = sa1[cur];
        *(bf16x8*)(ldsB + (wv * 128 + l) * 8)      = sb0[cur];
        *(bf16x8*)(ldsB + (wv * 128 + 64 + l) * 8) = sb1[cur];
        __syncthreads();
        if (i + 2 < NK) {
            int kk = (i + 2) * 32;
            sa0[cur] = *(const bf16x8*)(srcA0 + kk);
            sa1[cur] = *(const bf16x8*)(srcA1 + kk);
            sb0[cur] = *(const bf16x8*)(srcB0 + kk);
            sb1[cur] = *(const bf16x8*)(srcB1 + kk);
        }
        int g = l >> 4, rr = l & 15;
        bf16x8 a[4], b[4];
#pragma unroll
        for (int m = 0; m < 4; m++) a[m] = *(const bf16x8*)(ldsA + (g * 128 + wr * 64 + m * 16 + rr) * 8);
#pragma unroll
        for (int n = 0; n < 4; n++) b[n] = *(const bf16x8*)(ldsB + (g * 128 + wc * 64 + n * 16 + rr) * 8);
#pragma unroll
        for (int m = 0; m < 4; m++)
#pragma unroll
            for (int n = 0; n < 4; n++)
                acc[m][n] = __builtin_amdgcn_mfma_f32_16x16x32_bf16(a[m], b[n], acc[m][n], 0, 0, 0);
    }
    float* yb = ybuf + (size_t)s * YBS;
    int g = l >> 4, rr = l & 15;
#pragma unroll
    for (int m = 0; m < 4; m++)
#pragma unroll
        for (int n = 0; n < 4; n++) {
            int colg = ct * 128 + wc * 64 + n * 16 + rr;
#pragma unroll
            for (int j = 0; j < 4; j++) {
                int prow = prow0 + wr * 64 + m * 16 + g * 4 + j;
                yb[(size_t)prow * DIM + colg] = acc[m][n][j];
            }
        }
}

// ---------------- K5: combine  y = yb0+yb1+b2; out scatter; yT; ynorm ----------------
__global__ __launch_bounds__(256) void k_combine(
        const float* __restrict__ ybuf, const float* __restrict__ b2,
        const int* __restrict__ cnt, const int* __restrict__ offp,
        const int* __restrict__ list, const float* __restrict__ avgp,
        float* __restrict__ out, unsigned short* __restrict__ yT,
        float* __restrict__ ynorm) {
    int dt = blockIdx.x, rt = blockIdx.y;
    int prow0 = rt * 128;
    if (prow0 >= offp[8]) return;
    int e = 0;
#pragma unroll
    for (int k = 1; k < 8; k++) if (prow0 >= offp[k]) e = k;
    int offe = offp[e], cnt_e = cnt[e];
    float ap = avgp[e];
    int tid = threadIdx.x, l = tid & 63, w = tid >> 6;
    int d = dt * 64 + l;
    float bv = b2[e * DIM + d];
    for (int q = w * 8; q < w * 8 + 8; q++) {          // 4 rows per quad
        int prow = prow0 + q * 4;
        u16x4 pk;
        float ys2[4];
#pragma unroll
        for (int j = 0; j < 4; j++) {
            int pr = prow + j;
            int rl = pr - offe;
            float yv = ybuf[(size_t)pr * DIM + d] + ybuf[(size_t)YBS + (size_t)pr * DIM + d] + bv;
            bool valid = rl < cnt_e;
            if (valid) out[(size_t)list[e * TOKENS + rl] * DIM + d] = ap * yv;
            pk[j] = valid ? f2bf(yv) : (unsigned short)0;
            ys2[j] = valid ? yv * yv : 0.f;
        }
        *(u16x4*)(yT + (size_t)d * NPAD + prow) = pk;
#pragma unroll
        for (int j = 0; j < 4; j++) {
            float sv = ys2[j];
#pragma unroll
            for (int sh = 32; sh > 0; sh >>= 1) sv += __shfl_xor(sv, sh);
            if (l == 0) atomicAdd(&ynorm[prow + j], sv);
        }
    }
}

// ---------------- K6: Gram  ||Y^T Y||_F^2 per expert ----------------
__global__ __launch_bounds__(256) void k_gram(
        const unsigned short* __restrict__ yT, const int* __restrict__ cnt,
        const int* __restrict__ offp, float* __restrict__ offsq) {
    __shared__ unsigned short ldsA[128 * 32];
    __shared__ unsigned short ldsB[128 * 32];
    __shared__ float wsum[4];
    int e = blockIdx.z, dt = blockIdx.y, ct = blockIdx.x;
    int cnt_e = cnt[e];
    if (cnt_e <= 0) return;
    int offe = offp[e];
    int NK = (offp[e + 1] - offe) >> 5;                // padded count / 32, >= 4
    int tid = threadIdx.x, wv = tid >> 6, l = tid & 63;
    int wr = wv >> 1, wc = wv & 1;
    const unsigned short* srcA0 = yT + (size_t)(dt * 128 + l) * NPAD + offe + wv * 8;
    const unsigned short* srcA1 = yT + (size_t)(dt * 128 + 64 + l) * NPAD + offe + wv * 8;
    const unsigned short* srcB0 = yT + (size_t)(ct * 128 + l) * NPAD + offe + wv * 8;
    const unsigned short* srcB1 = yT + (size_t)(ct * 128 + 64 + l) * NPAD + offe + wv * 8;
    f32x4 acc[4][4] = {};
    bf16x8 sa0[2], sa1[2], sb0[2], sb1[2];
#pragma unroll
    for (int p = 0; p < 2; p++) {
        int kk = p * 32;
        sa0[p] = *(const bf16x8*)(srcA0 + kk);
        sa1[p] = *(const bf16x8*)(srcA1 + kk);
        sb0[p] = *(const bf16x8*)(srcB0 + kk);
        sb1[p] = *(const bf16x8*)(srcB1 + kk);
    }
    for (int i = 0; i < NK; i++) {
        int cur = i & 1;
        __syncthreads();
        *(bf16x8*)(ldsA + (wv * 128 + l) * 8)      = sa0[cur];
        *(bf16x8*)(ldsA + (wv * 128 + 64 + l) * 8) = sa1[cur];
        *(bf16x8*)(ldsB + (wv * 128 + l) * 8)      = sb0[cur];
        *(bf16x8*)(ldsB + (wv * 128 + 64 + l) * 8) = sb1[cur];
        __syncthreads();
        if (i + 2 < NK) {
            int kk = (i + 2) * 32;
            sa0[cur] = *(const bf16x8*)(srcA0 + kk);
            sa1[cur] = *(const bf16x8*)(srcA1 + kk);
            sb0[cur] = *(const bf16x8*)(srcB0 + kk);
            sb1[cur] = *(const bf16x8*)(srcB1 + kk);
        }
        int g = l >> 4, rr = l & 15;
        bf16x8 a[4], b[4];
#pragma unroll
        for (int m = 0; m < 4; m++) a[m] = *(const bf16x8*)(ldsA + (g * 128 + wr * 64 + m * 16 + rr) * 8);
#pragma unroll
        for (int n = 0; n < 4; n++) b[n] = *(const bf16x8*)(ldsB + (g * 128 + wc * 64 + n * 16 + rr) * 8);
#pragma unroll
        for (int m = 0; m < 4; m++)
#pragma unroll
            for (int n = 0; n < 4; n++)
                acc[m][n] = __builtin_amdgcn_mfma_f32_16x16x32_bf16(a[m], b[n], acc[m][n], 0, 0, 0);
    }
    float s = 0.f;
#pragma unroll
    for (int m = 0; m < 4; m++)
#pragma unroll
        for (int n = 0; n < 4; n++)
#pragma unroll
            for (int j = 0; j < 4; j++) s += acc[m][n][j] * acc[m][n][j];
#pragma unroll
    for (int sh = 32; sh > 0; sh >>= 1) s += __shfl_xor(s, sh);
    if (l == 0) wsum[wv] = s;
    __syncthreads();
    if (tid == 0) atomicAdd(&offsq[e], wsum[0] + wsum[1] + wsum[2] + wsum[3]);
}

// ---------------- K7: final loss ----------------
__global__ void k_loss(const int* __restrict__ cnt, const int* __restrict__ offp,
                       const float* __restrict__ offsq, const float* __restrict__ ynorm,
                       const float* __restrict__ lossp, float* __restrict__ out_loss) {
    __shared__ float ssq[8];
    int tid = threadIdx.x;
    if (tid < 8) ssq[tid] = 0.f;
    __syncthreads();
    int total = offp[8];
    for (int i = tid; i < total; i += blockDim.x) {
        int e = 0;
#pragma unroll
        for (int k = 0; k < 8; k++) if (i >= offp[k + 1]) e = k + 1;
        float s = ynorm[i];
        atomicAdd(&ssq[e], s * s);
    }
    __syncthreads();
    if (tid == 0) {
        float orth = 0.f;
        for (int e = 0; e < 8; e++) {
            if (cnt[e] > 0) {
                float cf = (float)cnt[e];
                orth += (offsq[e] - ssq[e]) / (cf * cf);
            }
        }
        out_loss[0] = lossp[0] + BETA * orth;
    }
}

extern "C" void kernel_launch(void* const* d_in, const int* in_sizes, int n_in,
                              void* d_out, int out_size, void* d_ws, size_t ws_size,
                              hipStream_t stream) {
    (void)in_sizes; (void)n_in; (void)out_size;
    const float* x  = (const float*)d_in[0];
    const float* gw = (const float*)d_in[1];
    const float* gb = (const float*)d_in[2];
    const float* w1 = (const float*)d_in[3];
    const float* b1 = (const float*)d_in[4];
    const float* w2 = (const float*)d_in[5];
    const float* b2 = (const float*)d_in[6];
    float* out = (float*)d_out;
    char* ws = (char*)d_ws;
    if (ws_size < (size_t)WS_TOTAL) return;

    int*   cnt    = (int*)(ws + WS_CNT);
    float* sump   = (float*)(ws + WS_SUMP);
    float* psum   = (float*)(ws + WS_PSUM);
    float* psumsq = (float*)(ws + WS_PSUMSQ);
    int*   offp   = (int*)(ws + WS_OFFP);
    float* avgp   = (float*)(ws + WS_AVGP);
    float* lossp  = (float*)(ws + WS_LOSSP);
    float* offsq  = (float*)(ws + WS_OFFSQ);
    float* ynorm  = (float*)(ws + WS_YNORM);
    int*   list   = (int*)(ws + WS_LIST);
    unsigned short* xb   = (unsigned short*)(ws + WS_XB);
    unsigned short* w1t  = (unsigned short*)(ws + WS_W1T);
    unsigned short* w2t  = (unsigned short*)(ws + WS_W2T);
    unsigned short* Hbuf = (unsigned short*)(ws + WS_HBUF);
    unsigned short* yT   = (unsigned short*)(ws + WS_YT);
    float* ybuf          = (float*)(ws + WS_YBUF);     // aliases w1t after gemm1

    hipMemsetAsync(ws, 0, WS_ZERO_END, stream);
    k_cvt_x<<<2048, 256, 0, stream>>>(x, xb);
    k_transpose_cvt<<<dim3(64, 16, 8), 256, 0, stream>>>(w1, w1t, 1024, 4096);
    k_transpose_cvt<<<dim3(16, 64, 8), 256, 0, stream>>>(w2, w2t, 4096, 1024);
    k_gate<<<256, 1024, 0, stream>>>(x, gw, gb, cnt, sump, psum, psumsq, list);
    k_finalize_gate<<<1, 64, 0, stream>>>(cnt, sump, psum, psumsq, offp, avgp, lossp);
    k_gemm1<<<dim3(32, 40), 256, 0, stream>>>(xb, w1t, b1, cnt, offp, list, Hbuf);
    k_gemm2<<<dim3(8, 40, 2), 256, 0, stream>>>(Hbuf, w2t, cnt, offp, ybuf);
    k_combine<<<dim3(16, 40), 256, 0, stream>>>(ybuf, b2, cnt, offp, list, avgp, out, yT, ynorm);
    k_gram<<<dim3(8, 8, 8), 256, 0, stream>>>(yT, cnt, offp, offsq);
    k_loss<<<1, 256, 0, stream>>>(cnt, offp, offsq, ynorm, lossp, out + (size_t)TOKENS * DIM);
}